// Round 2
// baseline (334.956 us; speedup 1.0000x reference)
//
#include <hip/hip_runtime.h>
#include <cstdint>
#include <cstddef>

#define B_N   16
#define G_N   128
#define FD_N  8192
#define BK    64

typedef unsigned short u16;
typedef u16  u16x4 __attribute__((ext_vector_type(4)));
typedef u16  u16x8 __attribute__((ext_vector_type(8)));
typedef __bf16 bf16x8 __attribute__((ext_vector_type(8)));
typedef float f32x16 __attribute__((ext_vector_type(16)));

// ---- ws layout (in floats) ----
#define STATS_SSQ_Q 0
#define STATS_SUM_Q 2048
#define STATS_SSQ_K 4096
#define STATS_SUM_K 6144
#define STATS_SSQ_N 8192
#define STATS_FLOATS 10240
#define CRED_OFF  10240          // 16 * 128*256 reduced C
#define PART_OFF  534528         // CRED_OFF + 16*32768; then ksplit*16*32768 partials

__device__ __forceinline__ u16 f2bf(float f) {
    uint32_t u = __float_as_uint(f);
    u += 0x7FFFu + ((u >> 16) & 1u);      // round-to-nearest-even
    return (u16)(u >> 16);
}

// Barrier that drains ONLY LDS ops (lgkmcnt) — pending global loads into
// private VGPRs stay in flight across the barrier. HIP's __syncthreads would
// emit s_waitcnt vmcnt(0) and kill the prefetch pipeline.
#define LDS_BARRIER() asm volatile("s_waitcnt lgkmcnt(0)\n\ts_barrier" ::: "memory")

// ================= K1: fused bf16 GEMM (C = q @ [k;n]^T per batch, K-split) + row stats =================
__global__ __launch_bounds__(512, 4)
void k_gemm(const float* __restrict__ q, const float* __restrict__ kM,
            const float* __restrict__ nM, float* __restrict__ ws,
            int ksplit, int kc)
{
    __shared__ __align__(16) u16 sA[G_N * BK];      // 16 KB, xor-swizzled
    __shared__ __align__(16) u16 sB[2 * G_N * BK];  // 32 KB

    const int tid = threadIdx.x;
    const int blk = blockIdx.x;
    const int b   = blk / ksplit;
    const int kch = blk - b * ksplit;
    const int niter = kc / BK;

    const size_t mat_off = (size_t)b * G_N * FD_N + (size_t)kch * kc + (size_t)(tid & 15) * 4;
    const float* qp = q  + mat_off;
    const float* kp = kM + mat_off;
    const float* np = nM + mat_off;
    const int r0 = tid >> 4;        // 0..31 base row
    const int c4 = tid & 15;        // float4-column within 64-wide K tile

    float4 la[4], lb[8];
    float aS[4] = {0.f,0.f,0.f,0.f}, aQ[4] = {0.f,0.f,0.f,0.f};
    float bS[8] = {0.f,0.f,0.f,0.f,0.f,0.f,0.f,0.f};
    float bQ[8] = {0.f,0.f,0.f,0.f,0.f,0.f,0.f,0.f};

    // prologue loads (kb = 0)
    #pragma unroll
    for (int i = 0; i < 4; ++i) la[i]   = *(const float4*)(qp + (size_t)(r0 + 32*i) * FD_N);
    #pragma unroll
    for (int i = 0; i < 4; ++i) lb[i]   = *(const float4*)(kp + (size_t)(r0 + 32*i) * FD_N);
    #pragma unroll
    for (int i = 0; i < 4; ++i) lb[4+i] = *(const float4*)(np + (size_t)(r0 + 32*i) * FD_N);

    const int lane  = tid & 63;
    const int wv    = tid >> 6;     // 8 waves
    const int wm    = wv >> 2;      // 0..1 -> 64-row block
    const int wn    = wv & 3;       // 0..3 -> 64-col block
    const int khalf = lane >> 5;
    const int lrow  = lane & 31;

    f32x16 acc[2][2];
    #pragma unroll
    for (int mb = 0; mb < 2; ++mb)
      #pragma unroll
      for (int nb = 0; nb < 2; ++nb)
        #pragma unroll
        for (int e = 0; e < 16; ++e) acc[mb][nb][e] = 0.f;

    // LDS write offsets (u16 units), 16B-chunk xor swizzle by (row & 7)
    int wA[4], wB[8];
    #pragma unroll
    for (int i = 0; i < 4; ++i) { int row = r0 + 32*i; wA[i] = row*BK + (((c4>>1) ^ (row&7))<<3) + ((c4&1)<<2); }
    #pragma unroll
    for (int i = 0; i < 8; ++i) { int row = r0 + 32*i; wB[i] = row*BK + (((c4>>1) ^ (row&7))<<3) + ((c4&1)<<2); }

    const int rA0 = wm*64 + lrow;
    const int rB0 = wn*64 + lrow;

    for (int kb = 0; kb < niter; ++kb) {
        LDS_BARRIER();    // previous iteration's MFMA ds_reads done; vm loads stay in flight
        #pragma unroll
        for (int i = 0; i < 4; ++i) {
            float4 v = la[i];
            aS[i] += v.x + v.y + v.z + v.w;
            aQ[i] += v.x*v.x + v.y*v.y + v.z*v.z + v.w*v.w;
            u16x4 h; h[0]=f2bf(v.x); h[1]=f2bf(v.y); h[2]=f2bf(v.z); h[3]=f2bf(v.w);
            *(u16x4*)(sA + wA[i]) = h;
        }
        #pragma unroll
        for (int i = 0; i < 8; ++i) {
            float4 v = lb[i];
            bS[i] += v.x + v.y + v.z + v.w;
            bQ[i] += v.x*v.x + v.y*v.y + v.z*v.z + v.w*v.w;
            u16x4 h; h[0]=f2bf(v.x); h[1]=f2bf(v.y); h[2]=f2bf(v.z); h[3]=f2bf(v.w);
            *(u16x4*)(sB + wB[i]) = h;
        }
        LDS_BARRIER();
        // prefetch next K tile (overlaps MFMA below, stays in flight across barriers)
        if (kb + 1 < niter) {
            const float* qn = qp + (kb+1)*BK;
            const float* kn = kp + (kb+1)*BK;
            const float* nn = np + (kb+1)*BK;
            #pragma unroll
            for (int i = 0; i < 4; ++i) la[i]   = *(const float4*)(qn + (size_t)(r0 + 32*i) * FD_N);
            #pragma unroll
            for (int i = 0; i < 4; ++i) lb[i]   = *(const float4*)(kn + (size_t)(r0 + 32*i) * FD_N);
            #pragma unroll
            for (int i = 0; i < 4; ++i) lb[4+i] = *(const float4*)(nn + (size_t)(r0 + 32*i) * FD_N);
        }
        #pragma unroll
        for (int s = 0; s < 4; ++s) {
            int chunk = s*2 + khalf;
            bf16x8 af[2], bf[2];
            #pragma unroll
            for (int mb = 0; mb < 2; ++mb) {
                int row = rA0 + mb*32;
                u16x8 raw = *(const u16x8*)(sA + row*BK + (((chunk) ^ (row&7))<<3));
                af[mb] = __builtin_bit_cast(bf16x8, raw);
            }
            #pragma unroll
            for (int nb = 0; nb < 2; ++nb) {
                int row = rB0 + nb*32;
                u16x8 raw = *(const u16x8*)(sB + row*BK + (((chunk) ^ (row&7))<<3));
                bf[nb] = __builtin_bit_cast(bf16x8, raw);
            }
            #pragma unroll
            for (int mb = 0; mb < 2; ++mb)
              #pragma unroll
              for (int nb = 0; nb < 2; ++nb)
                acc[mb][nb] = __builtin_amdgcn_mfma_f32_32x32x16_bf16(af[mb], bf[nb], acc[mb][nb], 0, 0, 0);
        }
    }

    // partial C write: C/D layout col=lane&31, row=(reg&3)+8*(reg>>2)+4*(lane>>5)
    float* part = ws + PART_OFF + (size_t)blk * (G_N * 256);
    #pragma unroll
    for (int mb = 0; mb < 2; ++mb)
      #pragma unroll
      for (int nb = 0; nb < 2; ++nb) {
        int col = wn*64 + nb*32 + lrow;
        int rbase = wm*64 + mb*32 + 4*khalf;
        #pragma unroll
        for (int reg = 0; reg < 16; ++reg) {
            int row = rbase + (reg & 3) + 8*(reg >> 2);
            part[(size_t)row * 256 + col] = acc[mb][nb][reg];
        }
      }

    // row stats: reduce across the 16 lanes sharing a row, then one atomic
    #pragma unroll
    for (int i = 0; i < 4; ++i) {
        float s = aS[i], qq = aQ[i];
        for (int m = 8; m >= 1; m >>= 1) { s += __shfl_xor(s, m, 64); qq += __shfl_xor(qq, m, 64); }
        if ((lane & 15) == 0) {
            int row = r0 + 32*i;
            atomicAdd(ws + STATS_SUM_Q + b*G_N + row, s);
            atomicAdd(ws + STATS_SSQ_Q + b*G_N + row, qq);
        }
    }
    #pragma unroll
    for (int i = 0; i < 8; ++i) {
        float s = bS[i], qq = bQ[i];
        for (int m = 8; m >= 1; m >>= 1) { s += __shfl_xor(s, m, 64); qq += __shfl_xor(qq, m, 64); }
        if ((lane & 15) == 0) {
            int row = r0 + 32*i;
            if (row < G_N) {
                atomicAdd(ws + STATS_SUM_K + b*G_N + row, s);
                atomicAdd(ws + STATS_SSQ_K + b*G_N + row, qq);
            } else {
                atomicAdd(ws + STATS_SSQ_N + b*G_N + (row - G_N), qq);
            }
        }
    }
}

// ================= K2: sum K-split partials (float4 vectorized) =================
__global__ __launch_bounds__(256)
void k_red(float* __restrict__ ws, int ksplit)
{
    int idx = blockIdx.x * 256 + threadIdx.x;      // 0..131071 float4 slots
    int b = idx >> 13;                             // 8192 float4 per batch image
    int w = idx & 8191;
    const float4* p = (const float4*)(ws + PART_OFF) + (size_t)b * ksplit * 8192 + w;
    float4 s = {0.f, 0.f, 0.f, 0.f};
    for (int ksi = 0; ksi < ksplit; ++ksi) {
        float4 v = p[(size_t)ksi * 8192];
        s.x += v.x; s.y += v.y; s.z += v.z; s.w += v.w;
    }
    ((float4*)(ws + CRED_OFF))[idx] = s;
}

// ================= K3: per-batch loss epilogue + weighted final combine =================
__global__ __launch_bounds__(256)
void k_epi(float* __restrict__ ws, float* __restrict__ out)
{
    const int b = blockIdx.x;
    const int t = threadIdx.x;
    __shared__ float invq[128], invk[128], invn[128], sqv[128], skv[128], ddq[128], ddk[128];
    __shared__ float sS[128 * 129];      // normalized S, padded stride vs transpose reads
    __shared__ float rbuf[4];

    const float c0 = (float)FD_N * 1e-6f * 1e-6f;   // FD*eps^2

    if (t < 128) {
        float iq = 1.f / fmaxf(sqrtf(ws[STATS_SSQ_Q + b*128 + t]), 1e-12f);
        invq[t] = iq;
        sqv[t]  = ws[STATS_SUM_Q + b*128 + t] * iq;
        float ik = 1.f / fmaxf(sqrtf(ws[STATS_SSQ_K + b*128 + t]), 1e-12f);
        invk[t] = ik;
        skv[t]  = ws[STATS_SUM_K + b*128 + t] * ik;
        invn[t] = 1.f / fmaxf(sqrtf(ws[STATS_SSQ_N + b*128 + t]), 1e-12f);
    }
    __syncthreads();
    const float* C = ws + CRED_OFF + (size_t)b * 32768;   // [128 rows][256 cols], cols 0..127 = k, 128..255 = n
    // stage normalized S into LDS
    for (int idx = t; idx < 16384; idx += 256) {
        int i = idx >> 7, j = idx & 127;
        sS[i*129 + j] = C[i*256 + j] * invq[i] * invk[j];
    }
    __syncthreads();
    if (t < 128) {
        float S_ii = sS[t*129 + t];
        ddq[t] = sqrtf(fmaxf(2.f - 2.f*S_ii + 2e-6f*(sqv[t]-skv[t]) + c0, 0.f));
        ddk[t] = sqrtf(fmaxf(2.f - 2.f*S_ii + 2e-6f*(skv[t]-sqv[t]) + c0, 0.f));
    }
    __syncthreads();

    float sm = 0.f, tri = 0.f, cyc = 0.f, ce = 0.f;
    for (int idx = t; idx < 16384; idx += 256) {
        int i = idx >> 7, j = idx & 127;
        float S_ij = sS[i*129 + j];
        float dd = S_ij - (i == j ? 1.f : 0.f);
        sm += dd * dd;
        if (i != j) {
            float dqk = sqrtf(fmaxf(2.f - 2.f*S_ij + 2e-6f*(sqv[i]-skv[j]) + c0, 0.f));
            tri += fmaxf(ddq[i] - dqk + 1.f, 0.f);
            float dkq = sqrtf(fmaxf(2.f - 2.f*S_ij + 2e-6f*(skv[j]-sqv[i]) + c0, 0.f));
            tri += fmaxf(ddk[j] - dkq + 1.f, 0.f);
            cyc += fabsf(S_ij - sS[j*129 + i]);
        }
    }
    // InfoNCE per row (logits bounded by 1/T=5, no max-shift needed)
    if (t < 128) {
        float iq = invq[t];
        float lp = sS[t*129 + t] * 5.0f;
        float ssum = __expf(lp);
        for (int j = 0; j < 128; ++j) {
            float ln = C[t*256 + 128 + j] * iq * invn[j] * 5.0f;
            ssum += __expf(ln);
        }
        ce = __logf(ssum) - lp;
    }

    // per-thread weighted contribution, single reduce, one atomic per block
    float contrib = sm / 16384.f + cyc / 16256.f + ce / 16384.f
                  + (float)(16 - b) * tri / 32512.f;
    for (int m = 32; m >= 1; m >>= 1) contrib += __shfl_xor(contrib, m, 64);
    int wvi = t >> 6, ln0 = t & 63;
    if (ln0 == 0) rbuf[wvi] = contrib;
    __syncthreads();
    if (t == 0) atomicAdd(out, rbuf[0] + rbuf[1] + rbuf[2] + rbuf[3]);
}

extern "C" void kernel_launch(void* const* d_in, const int* in_sizes, int n_in,
                              void* d_out, int out_size, void* d_ws, size_t ws_size,
                              hipStream_t stream)
{
    const float* q  = (const float*)d_in[0];
    const float* kM = (const float*)d_in[1];
    const float* nM = (const float*)d_in[2];
    float* ws  = (float*)d_ws;
    float* out = (float*)d_out;

    int ksplit = 32;
    while (ksplit > 1 &&
           ((size_t)PART_OFF + (size_t)ksplit * B_N * 32768) * sizeof(float) > ws_size)
        ksplit >>= 1;
    int kc = FD_N / ksplit;

    hipMemsetAsync(d_ws, 0, STATS_FLOATS * sizeof(float), stream);
    hipMemsetAsync(d_out, 0, sizeof(float), stream);
    k_gemm<<<B_N * ksplit, 512, 0, stream>>>(q, kM, nM, ws, ksplit, kc);
    k_red<<<(B_N * 32768 / 4) / 256, 256, 0, stream>>>(ws, ksplit);
    k_epi<<<B_N, 256, 0, stream>>>(ws, out);
}

// Round 3
// 231.713 us; speedup vs baseline: 1.4456x; 1.4456x over previous
//
#include <hip/hip_runtime.h>
#include <cstdint>
#include <cstddef>

#define B_N   16
#define G_N   128
#define FD_N  8192
#define BK    64

typedef unsigned short u16;
typedef u16  u16x4 __attribute__((ext_vector_type(4)));
typedef u16  u16x8 __attribute__((ext_vector_type(8)));
typedef __bf16 bf16x8 __attribute__((ext_vector_type(8)));
typedef float f32x16 __attribute__((ext_vector_type(16)));

// ---- ws layout (in floats) ----
#define STATS_SSQ_Q 0
#define STATS_SUM_Q 2048
#define STATS_SSQ_K 4096
#define STATS_SUM_K 6144
#define STATS_SSQ_N 8192
#define SM_ACC      10240        // [16][128] per-row sum of (S-δ)^2
#define CE_ACC      12288        // [16][128] per-row sum of exp(5*l_neg)
#define ZERO_FLOATS 14336
#define S_OFF       14336        // [16][128][128] normalized S
#define PART_OFF    276480       // (16*2*ksplit) x 128x128 fp32 partials

__device__ __forceinline__ u16 f2bf(float f) {
    uint32_t u = __float_as_uint(f);
    u += 0x7FFFu + ((u >> 16) & 1u);      // round-to-nearest-even
    return (u16)(u >> 16);
}

// Barrier draining ONLY LDS ops — pending global prefetch loads into private
// VGPRs stay in flight across the barrier (vs __syncthreads' vmcnt(0) drain).
#define LDS_BARRIER() asm volatile("s_waitcnt lgkmcnt(0)\n\ts_barrier" ::: "memory")

// ================= K1: bf16 GEMM, tile 128x128 (A=q, B=k or n), K-split, + row stats =================
// grid = B_N * 2 * ksplit; block = 512. acc = 32 VGPR/lane -> ~110 total, fits 4 waves/EU (2 blk/CU).
__global__ __launch_bounds__(512, 4)
void k_gemm(const float* __restrict__ q, const float* __restrict__ kM,
            const float* __restrict__ nM, float* __restrict__ ws,
            int ksplit, int kc)
{
    __shared__ __align__(16) u16 sA[G_N * BK];   // 16 KB
    __shared__ __align__(16) u16 sB[G_N * BK];   // 16 KB

    const int tid = threadIdx.x;
    const int blk = blockIdx.x;
    const int b    = blk / (2 * ksplit);
    const int rem  = blk - b * 2 * ksplit;
    const int half = rem / ksplit;         // 0 -> B=k, 1 -> B=n
    const int kch  = rem - half * ksplit;
    const int niter = kc / BK;

    const size_t mat_off = (size_t)b * G_N * FD_N + (size_t)kch * kc + (size_t)(tid & 15) * 4;
    const float* Ap = q + mat_off;
    const float* Bp = (half ? nM : kM) + mat_off;
    const int r0 = tid >> 4;        // 0..31 base row
    const int c4 = tid & 15;        // float4-column within 64-wide K tile

    float4 la[4], lb[4];
    float aS[4] = {0,0,0,0}, aQ[4] = {0,0,0,0};
    float bS[4] = {0,0,0,0}, bQ[4] = {0,0,0,0};

    #pragma unroll
    for (int i = 0; i < 4; ++i) la[i] = *(const float4*)(Ap + (size_t)(r0 + 32*i) * FD_N);
    #pragma unroll
    for (int i = 0; i < 4; ++i) lb[i] = *(const float4*)(Bp + (size_t)(r0 + 32*i) * FD_N);

    const int lane  = tid & 63;
    const int wv    = tid >> 6;     // 8 waves
    const int wm    = wv >> 2;      // 0..1 -> 64-row block
    const int wn    = wv & 3;       // 0..3 -> 32-col block
    const int khalf = lane >> 5;
    const int lrow  = lane & 31;

    f32x16 acc[2];
    #pragma unroll
    for (int mb = 0; mb < 2; ++mb)
      #pragma unroll
      for (int e = 0; e < 16; ++e) acc[mb][e] = 0.f;

    const int rA0 = wm*64 + lrow;
    const int rB0 = wn*32 + lrow;

    for (int kb = 0; kb < niter; ++kb) {
        LDS_BARRIER();   // prior MFMA ds_reads done; global loads stay in flight
        #pragma unroll
        for (int i = 0; i < 4; ++i) {
            float4 v = la[i];
            aS[i] += v.x + v.y + v.z + v.w;
            aQ[i] += v.x*v.x + v.y*v.y + v.z*v.z + v.w*v.w;
            u16x4 h; h[0]=f2bf(v.x); h[1]=f2bf(v.y); h[2]=f2bf(v.z); h[3]=f2bf(v.w);
            int row = r0 + 32*i;
            *(u16x4*)(sA + row*BK + (((c4>>1) ^ (row&7))<<3) + ((c4&1)<<2)) = h;
        }
        #pragma unroll
        for (int i = 0; i < 4; ++i) {
            float4 v = lb[i];
            bS[i] += v.x + v.y + v.z + v.w;
            bQ[i] += v.x*v.x + v.y*v.y + v.z*v.z + v.w*v.w;
            u16x4 h; h[0]=f2bf(v.x); h[1]=f2bf(v.y); h[2]=f2bf(v.z); h[3]=f2bf(v.w);
            int row = r0 + 32*i;
            *(u16x4*)(sB + row*BK + (((c4>>1) ^ (row&7))<<3) + ((c4&1)<<2)) = h;
        }
        LDS_BARRIER();
        if (kb + 1 < niter) {
            const float* An = Ap + (kb+1)*BK;
            const float* Bn = Bp + (kb+1)*BK;
            #pragma unroll
            for (int i = 0; i < 4; ++i) la[i] = *(const float4*)(An + (size_t)(r0 + 32*i) * FD_N);
            #pragma unroll
            for (int i = 0; i < 4; ++i) lb[i] = *(const float4*)(Bn + (size_t)(r0 + 32*i) * FD_N);
        }
        #pragma unroll
        for (int s = 0; s < 4; ++s) {
            int chunk = s*2 + khalf;
            bf16x8 af[2], bf;
            #pragma unroll
            for (int mb = 0; mb < 2; ++mb) {
                int row = rA0 + mb*32;
                u16x8 raw = *(const u16x8*)(sA + row*BK + ((chunk ^ (row&7))<<3));
                af[mb] = __builtin_bit_cast(bf16x8, raw);
            }
            {
                int row = rB0;
                u16x8 raw = *(const u16x8*)(sB + row*BK + ((chunk ^ (row&7))<<3));
                bf = __builtin_bit_cast(bf16x8, raw);
            }
            #pragma unroll
            for (int mb = 0; mb < 2; ++mb)
                acc[mb] = __builtin_amdgcn_mfma_f32_32x32x16_bf16(af[mb], bf, acc[mb], 0, 0, 0);
        }
    }

    // partial C write: C/D layout col=lane&31, row=(reg&3)+8*(reg>>2)+4*(lane>>5)
    float* part = ws + PART_OFF + (size_t)blk * (G_N * G_N);
    #pragma unroll
    for (int mb = 0; mb < 2; ++mb) {
        int col = wn*32 + lrow;
        int rbase = wm*64 + mb*32 + 4*khalf;
        #pragma unroll
        for (int reg = 0; reg < 16; ++reg) {
            int row = rbase + (reg & 3) + 8*(reg >> 2);
            part[(size_t)row * G_N + col] = acc[mb][reg];
        }
    }

    // row stats: reduce across the 16 lanes sharing a row, one atomic each
    #pragma unroll
    for (int i = 0; i < 4; ++i) {
        float sa = aS[i], qa = aQ[i], sb = bS[i], qb = bQ[i];
        for (int m = 8; m >= 1; m >>= 1) {
            sa += __shfl_xor(sa, m, 64); qa += __shfl_xor(qa, m, 64);
            sb += __shfl_xor(sb, m, 64); qb += __shfl_xor(qb, m, 64);
        }
        if ((lane & 15) == 0) {
            int row = r0 + 32*i;
            if (half == 0) {
                atomicAdd(ws + STATS_SUM_Q + b*G_N + row, sa);
                atomicAdd(ws + STATS_SSQ_Q + b*G_N + row, qa);
                atomicAdd(ws + STATS_SUM_K + b*G_N + row, sb);
                atomicAdd(ws + STATS_SSQ_K + b*G_N + row, qb);
            } else {
                atomicAdd(ws + STATS_SSQ_N + b*G_N + row, qb);
            }
        }
    }
}

// ================= K2: reduce partials + normalize + fold sm & InfoNCE-expsum =================
// grid = 512 x 256. idx -> (b, half, i, col4). half0: write S, sm partial; half1: ce exp partial.
__global__ __launch_bounds__(256)
void k_red2(float* __restrict__ ws, int ksplit)
{
    const int idx  = blockIdx.x * 256 + threadIdx.x;   // 0..131071
    const int col4 = idx & 31;
    const int i    = (idx >> 5) & 127;
    const int half = (idx >> 12) & 1;
    const int b    = idx >> 13;

    const float4* base = (const float4*)(ws + PART_OFF)
                       + ((size_t)((b*2 + half) * ksplit)) * 4096 + i*32 + col4;
    float4 s = {0.f, 0.f, 0.f, 0.f};
    for (int kch = 0; kch < ksplit; ++kch) {
        float4 v = base[(size_t)kch * 4096];
        s.x += v.x; s.y += v.y; s.z += v.z; s.w += v.w;
    }

    const float iq = 1.f / fmaxf(sqrtf(ws[STATS_SSQ_Q + b*G_N + i]), 1e-12f);

    if (half == 0) {
        float4 kss = *(const float4*)(ws + STATS_SSQ_K + b*G_N + col4*4);
        float4 S4;
        S4.x = s.x * iq / fmaxf(sqrtf(kss.x), 1e-12f);
        S4.y = s.y * iq / fmaxf(sqrtf(kss.y), 1e-12f);
        S4.z = s.z * iq / fmaxf(sqrtf(kss.z), 1e-12f);
        S4.w = s.w * iq / fmaxf(sqrtf(kss.w), 1e-12f);
        ((float4*)(ws + S_OFF))[(size_t)b*4096 + i*32 + col4] = S4;
        int j0 = col4*4;
        float d0 = S4.x - (j0+0 == i ? 1.f : 0.f);
        float d1 = S4.y - (j0+1 == i ? 1.f : 0.f);
        float d2 = S4.z - (j0+2 == i ? 1.f : 0.f);
        float d3 = S4.w - (j0+3 == i ? 1.f : 0.f);
        float sm = d0*d0 + d1*d1 + d2*d2 + d3*d3;
        for (int m = 16; m >= 1; m >>= 1) sm += __shfl_xor(sm, m, 64);
        if (col4 == 0) atomicAdd(ws + SM_ACC + b*G_N + i, sm);
    } else {
        float4 nss = *(const float4*)(ws + STATS_SSQ_N + b*G_N + col4*4);
        float e = __expf(s.x * iq / fmaxf(sqrtf(nss.x), 1e-12f) * 5.0f)
                + __expf(s.y * iq / fmaxf(sqrtf(nss.y), 1e-12f) * 5.0f)
                + __expf(s.z * iq / fmaxf(sqrtf(nss.z), 1e-12f) * 5.0f)
                + __expf(s.w * iq / fmaxf(sqrtf(nss.w), 1e-12f) * 5.0f);
        for (int m = 16; m >= 1; m >>= 1) e += __shfl_xor(e, m, 64);
        if (col4 == 0) atomicAdd(ws + CE_ACC + b*G_N + i, e);
    }
}

// ================= K3: tri/cyc/ce-final + weighted combine =================
// grid = 16 batches x 8 row-chunks = 128 blocks x 256 threads.
__global__ __launch_bounds__(256)
void k_epi(float* __restrict__ ws, float* __restrict__ out)
{
    const int b     = blockIdx.x >> 3;
    const int chunk = blockIdx.x & 7;
    const int i0    = chunk * 16;
    const int t     = threadIdx.x;
    __shared__ float sqv_s[128], skv_s[128], ddq_s[128], ddk_s[128];
    __shared__ float rbuf[4];

    const float c0 = (float)FD_N * 1e-6f * 1e-6f;
    const float* S = ws + S_OFF + (size_t)b * 16384;

    if (t < 128) {
        float iq = 1.f / fmaxf(sqrtf(ws[STATS_SSQ_Q + b*G_N + t]), 1e-12f);
        float sq = ws[STATS_SUM_Q + b*G_N + t] * iq;
        float ik = 1.f / fmaxf(sqrtf(ws[STATS_SSQ_K + b*G_N + t]), 1e-12f);
        float sk = ws[STATS_SUM_K + b*G_N + t] * ik;
        sqv_s[t] = sq; skv_s[t] = sk;
        float S_tt = S[t*128 + t];
        ddq_s[t] = sqrtf(fmaxf(2.f - 2.f*S_tt + 2e-6f*(sq - sk) + c0, 0.f));
        ddk_s[t] = sqrtf(fmaxf(2.f - 2.f*S_tt + 2e-6f*(sk - sq) + c0, 0.f));
    }
    __syncthreads();

    float tri = 0.f, cyc = 0.f, ce = 0.f, sm = 0.f;
    for (int p = t; p < 2048; p += 256) {
        int i = i0 + (p >> 7), j = p & 127;
        if (i != j) {
            float S_ij = S[i*128 + j];
            float dqk = sqrtf(fmaxf(2.f - 2.f*S_ij + 2e-6f*(sqv_s[i]-skv_s[j]) + c0, 0.f));
            tri += fmaxf(ddq_s[i] - dqk + 1.f, 0.f);
            float dkq = sqrtf(fmaxf(2.f - 2.f*S_ij + 2e-6f*(skv_s[j]-sqv_s[i]) + c0, 0.f));
            tri += fmaxf(ddk_s[j] - dkq + 1.f, 0.f);
            cyc += fabsf(S_ij - S[j*128 + i]);
        }
    }
    if (t < 16) {
        int r = i0 + t;
        float lp = 5.f * S[r*128 + r];
        ce = __logf(ws[CE_ACC + b*G_N + r] + __expf(lp)) - lp;
    }
    if (chunk == 0 && t < 128) sm = ws[SM_ACC + b*G_N + t];

    float contrib = sm / 16384.f + cyc / 16256.f + ce / 16384.f
                  + (float)(B_N - b) * tri / 32512.f;
    for (int m = 32; m >= 1; m >>= 1) contrib += __shfl_xor(contrib, m, 64);
    int wvi = t >> 6, ln0 = t & 63;
    if (ln0 == 0) rbuf[wvi] = contrib;
    __syncthreads();
    if (t == 0) atomicAdd(out, rbuf[0] + rbuf[1] + rbuf[2] + rbuf[3]);
}

extern "C" void kernel_launch(void* const* d_in, const int* in_sizes, int n_in,
                              void* d_out, int out_size, void* d_ws, size_t ws_size,
                              hipStream_t stream)
{
    const float* q  = (const float*)d_in[0];
    const float* kM = (const float*)d_in[1];
    const float* nM = (const float*)d_in[2];
    float* ws  = (float*)d_ws;
    float* out = (float*)d_out;

    int ksplit = 16;
    while (ksplit > 1 &&
           ((size_t)PART_OFF + (size_t)(B_N * 2 * ksplit) * (G_N * G_N)) * sizeof(float) > ws_size)
        ksplit >>= 1;
    int kc = FD_N / ksplit;

    hipMemsetAsync(d_ws, 0, ZERO_FLOATS * sizeof(float), stream);
    hipMemsetAsync(d_out, 0, sizeof(float), stream);
    k_gemm<<<B_N * 2 * ksplit, 512, 0, stream>>>(q, kM, nM, ws, ksplit, kc);
    k_red2<<<512, 256, 0, stream>>>(ws, ksplit);
    k_epi<<<B_N * 8, 256, 0, stream>>>(ws, out);
}